// Round 9
// baseline (125.656 us; speedup 1.0000x reference)
//
#include <hip/hip_runtime.h>

#define GX 432
#define GY 496
#define G_TOTAL (GX * GY) /* 214272, GZ=1, G_TOTAL%4==0 */
#define MAX_PTS 32
#define MAX_VOX 20000
#define CAP 64
#define INF_SENTINEL 0x7F7F7F7F
#define PREFIX_K 262144 /* ~131k in-range claims -> ~97k distinct cells >> 20000 */

typedef unsigned long long u64;

// IEEE float32 ops exactly matching the reference:
// c = floor((p - lo)/vs), lo = [0, -39.68, -3], vs = [.16,.16,4].
__device__ __forceinline__ int cell_of(float4 p, bool& ok) {
    float fx = floorf((p.x - 0.0f) / 0.16f);
    float fy = floorf((p.y + 39.68f) / 0.16f);
    float fz = floorf((p.z + 3.0f) / 4.0f);
    int cx = (int)fx, cy = (int)fy, cz = (int)fz;
    ok = (cx >= 0 && cx < GX && cy >= 0 && cy < GY && cz == 0);
    return cy * GX + cx;
}

// K1: fused initialization, int4-vectorized.
// rank[] MUST be inited to INF (round-4 crash lesson): under the prefix
// heuristic, cells whose first point is >= K are never ranked, but kAppend
// reads rank[c] for any in-range cell. dcount[0]=distinct count,
// dcount[1]=blocks-done counter for the last-block pattern.
__global__ __launch_bounds__(256) void kInit(int* __restrict__ first,
                                             int* __restrict__ rank,
                                             u64* __restrict__ bits,
                                             int* __restrict__ vcount,
                                             int* __restrict__ cellOfRank,
                                             int* __restrict__ dcount, int W) {
    int i = blockIdx.x * 256 + threadIdx.x;
    const int4 inf4 = make_int4(INF_SENTINEL, INF_SENTINEL, INF_SENTINEL,
                                INF_SENTINEL);
    const int4 m14 = make_int4(-1, -1, -1, -1);
    if (i < G_TOTAL / 4) {
        ((int4*)first)[i] = inf4;
        ((int4*)rank)[i] = inf4;
    }
    if (i < W) bits[i] = 0ull;
    if (i < MAX_VOX / 4) {
        ((int4*)vcount)[i] = m14;
        ((int4*)cellOfRank)[i] = m14;
    }
    if (i < 2) dcount[i] = 0;
}

// K2: FUSED points + distinct-count + guard. 2 pts/thread x 512 blocks
// (round-8 lesson: the 256-block/4pt version ran at 1 block/CU = 4 waves/CU
// — too little TLP to hide the atomicMin RETURN latency the distinct count
// needs; 512 blocks doubles the latency-hiding). One atomicAdd per block.
// Last-block pattern: threadfence + done-counter; the final block re-reads
// dcount and, ONLY if the prefix yielded < MAX_VOX distinct cells, repairs
// by claiming points K..n itself (filtered atomicMin — exact under stale
// reads since first[] only decreases). Rare path slow but correct; common
// path never takes it. Stream order guarantees kMark sees final first[].
__global__ __launch_bounds__(256) void kPointsCG(const float4* __restrict__ pts,
                                                 int* __restrict__ first,
                                                 int* __restrict__ dcount,
                                                 int K, int n) {
    __shared__ int wsh[4];
    __shared__ int repairFlag;
    int t = threadIdx.x;
    int i0 = blockIdx.x * 512 + t;
    int i1 = i0 + 256;
    int m = K - 1;
    float4 p0 = pts[i0 < K ? i0 : m];
    float4 p1 = pts[i1 < K ? i1 : m];
    bool k0, k1;
    int c0 = cell_of(p0, k0);
    int c1 = cell_of(p1, k1);
    int have = 0;
    if (k0 && i0 < K) have += (atomicMin(&first[c0], i0) == INF_SENTINEL);
    if (k1 && i1 < K) have += (atomicMin(&first[c1], i1) == INF_SENTINEL);
    for (int d = 32; d >= 1; d >>= 1) have += __shfl_down(have, d, 64);
    if ((t & 63) == 0) wsh[t >> 6] = have;
    __syncthreads();
    if (t == 0) {
        repairFlag = 0;
        int part = wsh[0] + wsh[1] + wsh[2] + wsh[3];
        if (part) atomicAdd(&dcount[0], part);
        __threadfence();
        if (atomicAdd(&dcount[1], 1) == (int)gridDim.x - 1) {
            int total = atomicAdd(&dcount[0], 0);
            repairFlag = (total < MAX_VOX);
        }
    }
    __syncthreads();
    if (repairFlag) {
        for (int i = K + t; i < n; i += 256) {
            float4 p = pts[i];
            bool ok;
            int c = cell_of(p, ok);
            if (ok && first[c] > i) atomicMin(&first[c], i);
        }
    }
}

// K3: set bit first[c] in the index-space bitmap. int4 sweep, 4 cells/thread.
// Distinct cells have distinct first indices -> low-contention atomicOr.
__global__ __launch_bounds__(256) void kMark(const int* __restrict__ first,
                                             u64* __restrict__ bits) {
    int q = blockIdx.x * 256 + threadIdx.x;
    if (q >= G_TOTAL / 4) return;
    int4 f = ((const int4*)first)[q];
    if (f.x != INF_SENTINEL) atomicOr(&bits[f.x >> 6], 1ull << (f.x & 63));
    if (f.y != INF_SENTINEL) atomicOr(&bits[f.y >> 6], 1ull << (f.y & 63));
    if (f.z != INF_SENTINEL) atomicOr(&bits[f.z >> 6], 1ull << (f.z & 63));
    if (f.w != INF_SENTINEL) atomicOr(&bits[f.w >> 6], 1ull << (f.w & 63));
}

// K4: per-word intra-block exclusive prefix (wordLocal) + per-block sums.
__global__ __launch_bounds__(256) void kScan(const u64* __restrict__ bits,
                                             unsigned* __restrict__ wordLocal,
                                             int* __restrict__ sums, int W) {
    __shared__ int wsum[4], wexc[4];
    int t = threadIdx.x;
    int wi = blockIdx.x * 256 + t;
    u64 mask = (wi < W) ? bits[wi] : 0ull;
    int v = __popcll(mask);
    int lane = t & 63, w = t >> 6;
    int x = v;
    for (int d = 1; d < 64; d <<= 1) {
        int y = __shfl_up(x, d, 64);
        if (lane >= d) x += y;
    }
    if (lane == 63) wsum[w] = x;
    __syncthreads();
    if (t == 0) {
        int a = 0;
        for (int j = 0; j < 4; j++) { wexc[j] = a; a += wsum[j]; }
        sums[blockIdx.x] = a;
    }
    __syncthreads();
    if (wi < W) wordLocal[wi] = (unsigned)(wexc[w] + x - v);
}

// K5: materialize rank PER CELL. int4 sweep (4 cells/thread, 210 blocks);
// the bits/wordLocal random loads are issued UNCONDITIONALLY via clamped
// word index (select after load) -> MLP=8 on the random-read chain
// (round-6's kPoints transform applied here). Each block redundantly
// exclusive-scans the (<=256) block sums in LDS. Also writes cellOfRank
// and num_voxels (block 0).
__global__ __launch_bounds__(256) void kRank(const int* __restrict__ first,
                                             const u64* __restrict__ bits,
                                             const unsigned* __restrict__ wordLocal,
                                             const int* __restrict__ sums,
                                             int nbW,
                                             int* __restrict__ rank,
                                             int* __restrict__ cellOfRank,
                                             float* __restrict__ nvOut) {
    __shared__ int sExc[256];
    __shared__ int wsum[4], wexc[4];
    int t = threadIdx.x;
    int v = (t < nbW) ? sums[t] : 0;
    int lane = t & 63, w = t >> 6;
    int x = v;
    for (int d = 1; d < 64; d <<= 1) {
        int y = __shfl_up(x, d, 64);
        if (lane >= d) x += y;
    }
    if (lane == 63) wsum[w] = x;
    __syncthreads();
    if (t == 0) {
        int a = 0;
        for (int j = 0; j < 4; j++) { wexc[j] = a; a += wsum[j]; }
        if (blockIdx.x == 0) nvOut[0] = (float)(a < MAX_VOX ? a : MAX_VOX);
    }
    __syncthreads();
    sExc[t] = wexc[w] + x - v;
    __syncthreads();

    int q = blockIdx.x * 256 + t;
    if (q >= G_TOTAL / 4) return;
    int4 f4 = ((const int4*)first)[q];
    int f[4] = {f4.x, f4.y, f4.z, f4.w};
    int wf[4];
    u64 bw[4];
    unsigned wl[4];
#pragma unroll
    for (int j = 0; j < 4; j++) {
        int ff = (f[j] != INF_SENTINEL) ? f[j] : 0;  // clamp: word 0 exists
        wf[j] = ff >> 6;
        bw[j] = bits[wf[j]];       // unconditional -> MLP
        wl[j] = wordLocal[wf[j]];  // unconditional -> MLP
    }
    int base = q * 4;
#pragma unroll
    for (int j = 0; j < 4; j++) {
        if (f[j] == INF_SENTINEL) continue;
        int b = f[j] & 63;
        u64 lowmask = (b == 0) ? 0ull : ((~0ull) >> (64 - b));
        int vr = sExc[wf[j] >> 8] + (int)wl[j] + __popcll(bw[j] & lowmask);
        rank[base + j] = vr;
        if (vr < MAX_VOX) cellOfRank[vr] = base + j;
    }
}

// K6: append pass, 4 consecutive points/thread (64B contiguous per lane).
// Cells recomputed from pts (bitwise-identical IEEE ops; no lin[] array).
// rank loads issued UNCONDITIONALLY via clamped index (MLP=4 on the 2-level
// pts->rank chain). NEW: stores the float4 payload into listP alongside the
// index in listI (fire-and-forget scattered stores) so passF never has to
// random-gather from the 32MB pts array. Unsigned compare (round-4 lesson).
__global__ __launch_bounds__(256) void kAppend(const float4* __restrict__ pts,
                                               const int* __restrict__ rank,
                                               int* __restrict__ vcount,
                                               int* __restrict__ listI,
                                               float4* __restrict__ listP,
                                               int n) {
    int gid = blockIdx.x * 256 + threadIdx.x;
    int nq = n >> 2;
    if (gid < nq) {
        int base = gid * 4;
        float4 p0 = pts[base + 0];
        float4 p1 = pts[base + 1];
        float4 p2 = pts[base + 2];
        float4 p3 = pts[base + 3];
        bool k0, k1, k2, k3;
        int c0 = cell_of(p0, k0);
        int c1 = cell_of(p1, k1);
        int c2 = cell_of(p2, k2);
        int c3 = cell_of(p3, k3);
        int r0 = rank[k0 ? c0 : 0];
        int r1 = rank[k1 ? c1 : 0];
        int r2 = rank[k2 ? c2 : 0];
        int r3 = rank[k3 ? c3 : 0];
        r0 = k0 ? r0 : INF_SENTINEL;
        r1 = k1 ? r1 : INF_SENTINEL;
        r2 = k2 ? r2 : INF_SENTINEL;
        r3 = k3 ? r3 : INF_SENTINEL;
        if ((unsigned)r0 < MAX_VOX) {
            int pos = atomicAdd(&vcount[r0], 1) + 1;
            if (pos < CAP) { listI[r0 * CAP + pos] = base + 0; listP[r0 * CAP + pos] = p0; }
        }
        if ((unsigned)r1 < MAX_VOX) {
            int pos = atomicAdd(&vcount[r1], 1) + 1;
            if (pos < CAP) { listI[r1 * CAP + pos] = base + 1; listP[r1 * CAP + pos] = p1; }
        }
        if ((unsigned)r2 < MAX_VOX) {
            int pos = atomicAdd(&vcount[r2], 1) + 1;
            if (pos < CAP) { listI[r2 * CAP + pos] = base + 2; listP[r2 * CAP + pos] = p2; }
        }
        if ((unsigned)r3 < MAX_VOX) {
            int pos = atomicAdd(&vcount[r3], 1) + 1;
            if (pos < CAP) { listI[r3 * CAP + pos] = base + 3; listP[r3 * CAP + pos] = p3; }
        }
    }
    // scalar tail (n % 4), executed once
    if (gid == 0) {
        for (int i = nq << 2; i < n; i++) {
            float4 p = pts[i];
            bool ok;
            int c = cell_of(p, ok);
            if (!ok) continue;
            int vr = rank[c];
            if ((unsigned)vr >= MAX_VOX) continue;
            int pos = atomicAdd(&vcount[vr], 1) + 1;
            if (pos < CAP) { listI[vr * CAP + pos] = i; listP[vr * CAP + pos] = p; }
        }
    }
}

// K7: 4 voxels per 256-thread block (one wave each). Candidates' payloads
// are read COALESCED from listP (L2-dirty from kAppend) into LDS — no
// random pts gather. Counting-sort the indices, write all 32 slots +
// num_points + coors (no d_out pre-memset needed).
__global__ __launch_bounds__(256) void passF(const int* __restrict__ vcount,
                                             const int* __restrict__ cellOfRank,
                                             const int* __restrict__ listI,
                                             const float4* __restrict__ listP,
                                             float4* __restrict__ voxOut,
                                             float* __restrict__ coorsOut,
                                             float* __restrict__ npOut) {
    __shared__ int s[4][CAP];
    __shared__ float4 sp[4][CAP];
    __shared__ int slotSrc[4][MAX_PTS];
    int w = threadIdx.x >> 6, lane = threadIdx.x & 63;
    int v = blockIdx.x * 4 + w;
    int cnt = vcount[v] + 1;
    int m = cnt < CAP ? cnt : CAP;
    int idx = 0x7FFFFFFF;
    if (lane < m) {
        idx = listI[v * CAP + lane];
        sp[w][lane] = listP[v * CAP + lane];
    }
    s[w][lane] = idx;
    if (lane < MAX_PTS) slotSrc[w][lane] = -1;
    __syncthreads();
    int my = s[w][lane];
    int r = 0;
#pragma unroll
    for (int j = 0; j < CAP; j++) r += (s[w][j] < my) ? 1 : 0;  // broadcast
    if (lane < m && r < MAX_PTS) slotSrc[w][r] = lane;
    __syncthreads();
    if (lane < MAX_PTS) {
        int src = slotSrc[w][lane];
        float4 val = make_float4(0.f, 0.f, 0.f, 0.f);
        if (src >= 0) val = sp[w][src];
        voxOut[(size_t)v * MAX_PTS + lane] = val;
    }
    if (lane == 0) {
        npOut[v] = (float)(cnt < MAX_PTS ? cnt : MAX_PTS);
        int cell = cellOfRank[v];
        if (cell < 0) {
            coorsOut[3 * v + 0] = -1.0f;
            coorsOut[3 * v + 1] = -1.0f;
            coorsOut[3 * v + 2] = -1.0f;
        } else {
            coorsOut[3 * v + 0] = 0.0f;  // cz (GZ==1)
            coorsOut[3 * v + 1] = (float)(cell / GX);
            coorsOut[3 * v + 2] = (float)(cell % GX);
        }
    }
}

extern "C" void kernel_launch(void* const* d_in, const int* in_sizes, int n_in,
                              void* d_out, int out_size, void* d_ws, size_t ws_size,
                              hipStream_t stream) {
    const float4* pts = (const float4*)d_in[0];
    int n = in_sizes[0] / 4;    // 2,000,000
    int W = (n + 63) >> 6;      // 31250 bitmap words
    int nbW = (W + 255) / 256;  // 123
    int K = PREFIX_K < n ? PREFIX_K : n;

    char* ws = (char*)d_ws;
    size_t off = 0;
    auto alloc = [&](size_t bytes) -> void* {
        void* p = (void*)(ws + off);
        off = (off + bytes + 255) & ~(size_t)255;
        return p;
    };
    int* first = (int*)alloc((size_t)G_TOTAL * 4);
    u64* bits = (u64*)alloc((size_t)W * 8);
    unsigned* wordLocal = (unsigned*)alloc((size_t)W * 4);
    int* sums = (int*)alloc(256 * 4);
    int* rank = (int*)alloc((size_t)G_TOTAL * 4);
    int* vcount = (int*)alloc((size_t)MAX_VOX * 4);
    int* cellOfRank = (int*)alloc((size_t)MAX_VOX * 4);
    int* dcount = (int*)alloc(256 * 4);
    float4* listP = (float4*)alloc((size_t)MAX_VOX * CAP * 16);
    int* listI = (int*)alloc((size_t)MAX_VOX * CAP * 4);
    (void)ws_size;
    (void)n_in;
    (void)out_size;

    float* out = (float*)d_out;
    float4* voxOut = (float4*)out;                          // 20000*32*4
    float* coorsOut = out + (size_t)MAX_VOX * MAX_PTS * 4;  // 20000*3
    float* npOut = coorsOut + (size_t)MAX_VOX * 3;          // 20000
    float* nvOut = npOut + MAX_VOX;                         // 1

    // kInit grid must cover max(G_TOTAL/4, W, MAX_VOX/4) elements
    int mxI = G_TOTAL / 4;
    if (W > mxI) mxI = W;
    int nbI = (mxI + 255) / 256;            // 210
    int nbK = (K + 511) / 512;              // 512 (prefix, 2 pts/thread)
    int nbC4 = (G_TOTAL / 4 + 255) / 256;   // 210
    int nbA = ((n >> 2) + 255) / 256;       // 1954 (4 pts/thread)

    kInit<<<nbI, 256, 0, stream>>>(first, rank, bits, vcount, cellOfRank,
                                   dcount, W);
    kPointsCG<<<nbK, 256, 0, stream>>>(pts, first, dcount, K, n);
    kMark<<<nbC4, 256, 0, stream>>>(first, bits);
    kScan<<<nbW, 256, 0, stream>>>(bits, wordLocal, sums, W);
    kRank<<<nbC4, 256, 0, stream>>>(first, bits, wordLocal, sums, nbW, rank,
                                    cellOfRank, nvOut);
    kAppend<<<nbA, 256, 0, stream>>>(pts, rank, vcount, listI, listP, n);
    passF<<<MAX_VOX / 4, 256, 0, stream>>>(vcount, cellOfRank, listI, listP,
                                           voxOut, coorsOut, npOut);
}

// Round 10
// 120.713 us; speedup vs baseline: 1.0410x; 1.0410x over previous
//
#include <hip/hip_runtime.h>

#define GX 432
#define GY 496
#define G_TOTAL (GX * GY) /* 214272, GZ=1, G_TOTAL%4==0 */
#define MAX_PTS 32
#define MAX_VOX 20000
#define CAP 64
#define INF_SENTINEL 0x7F7F7F7F
#define PREFIX_K 262144 /* ~131k in-range claims -> ~97k distinct cells >> 20000 */

typedef unsigned long long u64;

// IEEE float32 ops exactly matching the reference:
// c = floor((p - lo)/vs), lo = [0, -39.68, -3], vs = [.16,.16,4].
__device__ __forceinline__ int cell_of(float4 p, bool& ok) {
    float fx = floorf((p.x - 0.0f) / 0.16f);
    float fy = floorf((p.y + 39.68f) / 0.16f);
    float fz = floorf((p.z + 3.0f) / 4.0f);
    int cx = (int)fx, cy = (int)fy, cz = (int)fz;
    ok = (cx >= 0 && cx < GX && cy >= 0 && cy < GY && cz == 0);
    return cy * GX + cx;
}

// K1: fused initialization, int4-vectorized.
// rank[] MUST be inited to INF (round-4 crash lesson): under the prefix
// heuristic, cells whose first point is >= K are never ranked, but kAppend
// reads rank[c] for any in-range cell. dcount[0]=distinct count,
// dcount[1]=blocks-done counter for countDG's last-block pattern.
__global__ __launch_bounds__(256) void kInit(int* __restrict__ first,
                                             int* __restrict__ rank,
                                             u64* __restrict__ bits,
                                             int* __restrict__ vcount,
                                             int* __restrict__ cellOfRank,
                                             int* __restrict__ dcount, int W) {
    int i = blockIdx.x * 256 + threadIdx.x;
    const int4 inf4 = make_int4(INF_SENTINEL, INF_SENTINEL, INF_SENTINEL,
                                INF_SENTINEL);
    const int4 m14 = make_int4(-1, -1, -1, -1);
    if (i < G_TOTAL / 4) {
        ((int4*)first)[i] = inf4;
        ((int4*)rank)[i] = inf4;
    }
    if (i < W) bits[i] = 0ull;
    if (i < MAX_VOX / 4) {
        ((int4*)vcount)[i] = m14;
        ((int4*)cellOfRank)[i] = m14;
    }
    if (i < 2) dcount[i] = 0;
}

// K2: prefix-only point pass, 4 pts/thread (MLP=4, round-6-validated shape),
// PURE fire-and-forget atomicMin — the single change vs round 8: consuming
// the atomicMin return value forces a per-thread memory round-trip (round-5
// lesson at wave granularity; round-8/9 evidence at block granularity).
// Distinct-count moved to countDG.
__global__ __launch_bounds__(256) void kPointsFF(const float4* __restrict__ pts,
                                                 int* __restrict__ first,
                                                 int K) {
    int i0 = blockIdx.x * 1024 + threadIdx.x;
    int i1 = i0 + 256, i2 = i0 + 512, i3 = i0 + 768;
    int m = K - 1;
    float4 p0 = pts[i0 < K ? i0 : m];
    float4 p1 = pts[i1 < K ? i1 : m];
    float4 p2 = pts[i2 < K ? i2 : m];
    float4 p3 = pts[i3 < K ? i3 : m];
    bool k0, k1, k2, k3;
    int c0 = cell_of(p0, k0);
    int c1 = cell_of(p1, k1);
    int c2 = cell_of(p2, k2);
    int c3 = cell_of(p3, k3);
    if (k0 && i0 < K) atomicMin(&first[c0], i0);
    if (k1 && i1 < K) atomicMin(&first[c1], i1);
    if (k2 && i2 < K) atomicMin(&first[c2], i2);
    if (k3 && i3 < K) atomicMin(&first[c3], i3);
}

// K3: FUSED distinct-count + guard (round-7's countD+guard in one dispatch).
// int4 sweep of the L2-resident first[] (857 KB), block-reduce, one
// atomicAdd per block. Last-block pattern: threadfence + done-counter; the
// final block re-reads the total and, ONLY if the prefix yielded < MAX_VOX
// distinct cells, repairs by claiming points K..n itself (filtered atomicMin
// — exact under stale reads since first[] only decreases). Rare path slow
// (1 block) but correct for any input; common path never takes it.
// Stream order guarantees kMark sees the final first[].
__global__ __launch_bounds__(256) void countDG(const float4* __restrict__ pts,
                                               int* __restrict__ first,
                                               int* __restrict__ dcount,
                                               int K, int n) {
    __shared__ int wsh[4];
    __shared__ int repairFlag;
    int t = threadIdx.x;
    int q = blockIdx.x * 256 + t;
    int have = 0;
    if (q < G_TOTAL / 4) {
        int4 f = ((const int4*)first)[q];
        have = (f.x != INF_SENTINEL) + (f.y != INF_SENTINEL) +
               (f.z != INF_SENTINEL) + (f.w != INF_SENTINEL);
    }
    for (int d = 32; d >= 1; d >>= 1) have += __shfl_down(have, d, 64);
    if ((t & 63) == 0) wsh[t >> 6] = have;
    __syncthreads();
    if (t == 0) {
        repairFlag = 0;
        int part = wsh[0] + wsh[1] + wsh[2] + wsh[3];
        if (part) atomicAdd(&dcount[0], part);
        __threadfence();
        if (atomicAdd(&dcount[1], 1) == (int)gridDim.x - 1) {
            int total = atomicAdd(&dcount[0], 0);
            repairFlag = (total < MAX_VOX);
        }
    }
    __syncthreads();
    if (repairFlag) {
        for (int i = K + t; i < n; i += 256) {
            float4 p = pts[i];
            bool ok;
            int c = cell_of(p, ok);
            if (ok && first[c] > i) atomicMin(&first[c], i);
        }
    }
}

// K4: set bit first[c] in the index-space bitmap. Distinct cells have
// distinct first indices; words shared by ~3 cells -> low-contention atomicOr.
__global__ __launch_bounds__(256) void kMark(const int* __restrict__ first,
                                             u64* __restrict__ bits) {
    int c = blockIdx.x * 256 + threadIdx.x;
    if (c >= G_TOTAL) return;
    int f = first[c];
    if (f != INF_SENTINEL) atomicOr(&bits[f >> 6], 1ull << (f & 63));
}

// K5: per-word intra-block exclusive prefix (wordLocal) + per-block sums.
__global__ __launch_bounds__(256) void kScan(const u64* __restrict__ bits,
                                             unsigned* __restrict__ wordLocal,
                                             int* __restrict__ sums, int W) {
    __shared__ int wsum[4], wexc[4];
    int t = threadIdx.x;
    int wi = blockIdx.x * 256 + t;
    u64 mask = (wi < W) ? bits[wi] : 0ull;
    int v = __popcll(mask);
    int lane = t & 63, w = t >> 6;
    int x = v;
    for (int d = 1; d < 64; d <<= 1) {
        int y = __shfl_up(x, d, 64);
        if (lane >= d) x += y;
    }
    if (lane == 63) wsum[w] = x;
    __syncthreads();
    if (t == 0) {
        int a = 0;
        for (int j = 0; j < 4; j++) { wexc[j] = a; a += wsum[j]; }
        sums[blockIdx.x] = a;
    }
    __syncthreads();
    if (wi < W) wordLocal[wi] = (unsigned)(wexc[w] + x - v);
}

// K6: materialize rank PER CELL (so the 2M-point append pass does only ONE
// random read). Each block redundantly exclusive-scans the (<=256) block
// sums in LDS. Also writes cellOfRank and num_voxels (block 0).
__global__ __launch_bounds__(256) void kRank(const int* __restrict__ first,
                                             const u64* __restrict__ bits,
                                             const unsigned* __restrict__ wordLocal,
                                             const int* __restrict__ sums,
                                             int nbW,
                                             int* __restrict__ rank,
                                             int* __restrict__ cellOfRank,
                                             float* __restrict__ nvOut) {
    __shared__ int sExc[256];
    __shared__ int wsum[4], wexc[4];
    int t = threadIdx.x;
    int v = (t < nbW) ? sums[t] : 0;
    int lane = t & 63, w = t >> 6;
    int x = v;
    for (int d = 1; d < 64; d <<= 1) {
        int y = __shfl_up(x, d, 64);
        if (lane >= d) x += y;
    }
    if (lane == 63) wsum[w] = x;
    __syncthreads();
    if (t == 0) {
        int a = 0;
        for (int j = 0; j < 4; j++) { wexc[j] = a; a += wsum[j]; }
        if (blockIdx.x == 0) nvOut[0] = (float)(a < MAX_VOX ? a : MAX_VOX);
    }
    __syncthreads();
    sExc[t] = wexc[w] + x - v;
    __syncthreads();

    int c = blockIdx.x * 256 + t;
    if (c >= G_TOTAL) return;
    int f = first[c];
    if (f == INF_SENTINEL) return;
    int wf = f >> 6, b = f & 63;
    u64 lowmask = (b == 0) ? 0ull : ((~0ull) >> (64 - b));
    int vr = sExc[wf >> 8] + (int)wordLocal[wf] + __popcll(bits[wf] & lowmask);
    rank[c] = vr;
    if (vr < MAX_VOX) cellOfRank[vr] = c;
}

// K7: append pass, 4 consecutive points/thread (64B contiguous per lane).
// Cells recomputed from pts (bitwise-identical IEEE ops; no lin[] array).
// rank loads issued UNCONDITIONALLY via clamped index (MLP=4 on the 2-level
// pts->rank chain). Unsigned compare (round-4 lesson).
__global__ __launch_bounds__(256) void kAppend(const float4* __restrict__ pts,
                                               const int* __restrict__ rank,
                                               int* __restrict__ vcount,
                                               int* __restrict__ list, int n) {
    int gid = blockIdx.x * 256 + threadIdx.x;
    int nq = n >> 2;
    if (gid < nq) {
        int base = gid * 4;
        float4 p0 = pts[base + 0];
        float4 p1 = pts[base + 1];
        float4 p2 = pts[base + 2];
        float4 p3 = pts[base + 3];
        bool k0, k1, k2, k3;
        int c0 = cell_of(p0, k0);
        int c1 = cell_of(p1, k1);
        int c2 = cell_of(p2, k2);
        int c3 = cell_of(p3, k3);
        int r0 = rank[k0 ? c0 : 0];
        int r1 = rank[k1 ? c1 : 0];
        int r2 = rank[k2 ? c2 : 0];
        int r3 = rank[k3 ? c3 : 0];
        r0 = k0 ? r0 : INF_SENTINEL;
        r1 = k1 ? r1 : INF_SENTINEL;
        r2 = k2 ? r2 : INF_SENTINEL;
        r3 = k3 ? r3 : INF_SENTINEL;
#pragma unroll
        for (int j = 0; j < 4; j++) {
            int vr = j == 0 ? r0 : j == 1 ? r1 : j == 2 ? r2 : r3;
            if ((unsigned)vr >= MAX_VOX) continue;
            int pos = atomicAdd(&vcount[vr], 1) + 1;
            if (pos < CAP) list[vr * CAP + pos] = base + j;
        }
    }
    // scalar tail (n % 4), executed once
    if (gid == 0) {
        for (int i = nq << 2; i < n; i++) {
            float4 p = pts[i];
            bool ok;
            int c = cell_of(p, ok);
            if (!ok) continue;
            int vr = rank[c];
            if ((unsigned)vr >= MAX_VOX) continue;
            int pos = atomicAdd(&vcount[vr], 1) + 1;
            if (pos < CAP) list[vr * CAP + pos] = i;
        }
    }
}

// K8: 4 voxels per 256-thread block (one wave each). Counting-sort the
// collected indices (LDS broadcast reads), write all 32 slots + num_points
// + coors (so no d_out pre-memset is needed).
__global__ __launch_bounds__(256) void passF(const float4* __restrict__ pts,
                                             const int* __restrict__ vcount,
                                             const int* __restrict__ cellOfRank,
                                             const int* __restrict__ list,
                                             float4* __restrict__ voxOut,
                                             float* __restrict__ coorsOut,
                                             float* __restrict__ npOut) {
    __shared__ int s[4][CAP];
    __shared__ int slotPt[4][MAX_PTS];
    int w = threadIdx.x >> 6, lane = threadIdx.x & 63;
    int v = blockIdx.x * 4 + w;
    int cnt = vcount[v] + 1;
    int m = cnt < CAP ? cnt : CAP;
    s[w][lane] = (lane < m) ? list[v * CAP + lane] : 0x7FFFFFFF;
    if (lane < MAX_PTS) slotPt[w][lane] = -1;
    __syncthreads();
    int my = s[w][lane];
    int r = 0;
#pragma unroll
    for (int j = 0; j < CAP; j++) r += (s[w][j] < my) ? 1 : 0;  // broadcast
    if (lane < m && r < MAX_PTS) slotPt[w][r] = my;
    __syncthreads();
    if (lane < MAX_PTS) {
        int p = slotPt[w][lane];
        float4 val = make_float4(0.f, 0.f, 0.f, 0.f);
        if (p >= 0) val = pts[p];
        voxOut[(size_t)v * MAX_PTS + lane] = val;
    }
    if (lane == 0) {
        npOut[v] = (float)(cnt < MAX_PTS ? cnt : MAX_PTS);
        int cell = cellOfRank[v];
        if (cell < 0) {
            coorsOut[3 * v + 0] = -1.0f;
            coorsOut[3 * v + 1] = -1.0f;
            coorsOut[3 * v + 2] = -1.0f;
        } else {
            coorsOut[3 * v + 0] = 0.0f;  // cz (GZ==1)
            coorsOut[3 * v + 1] = (float)(cell / GX);
            coorsOut[3 * v + 2] = (float)(cell % GX);
        }
    }
}

extern "C" void kernel_launch(void* const* d_in, const int* in_sizes, int n_in,
                              void* d_out, int out_size, void* d_ws, size_t ws_size,
                              hipStream_t stream) {
    const float4* pts = (const float4*)d_in[0];
    int n = in_sizes[0] / 4;    // 2,000,000
    int W = (n + 63) >> 6;      // 31250 bitmap words
    int nbW = (W + 255) / 256;  // 123
    int K = PREFIX_K < n ? PREFIX_K : n;

    char* ws = (char*)d_ws;
    size_t off = 0;
    auto alloc = [&](size_t bytes) -> void* {
        void* p = (void*)(ws + off);
        off = (off + bytes + 255) & ~(size_t)255;
        return p;
    };
    int* first = (int*)alloc((size_t)G_TOTAL * 4);
    u64* bits = (u64*)alloc((size_t)W * 8);
    unsigned* wordLocal = (unsigned*)alloc((size_t)W * 4);
    int* sums = (int*)alloc(256 * 4);
    int* rank = (int*)alloc((size_t)G_TOTAL * 4);
    int* vcount = (int*)alloc((size_t)MAX_VOX * 4);
    int* cellOfRank = (int*)alloc((size_t)MAX_VOX * 4);
    int* dcount = (int*)alloc(256 * 4);
    int* list = (int*)alloc((size_t)MAX_VOX * CAP * 4);
    (void)ws_size;
    (void)n_in;
    (void)out_size;

    float* out = (float*)d_out;
    float4* voxOut = (float4*)out;                          // 20000*32*4
    float* coorsOut = out + (size_t)MAX_VOX * MAX_PTS * 4;  // 20000*3
    float* npOut = coorsOut + (size_t)MAX_VOX * 3;          // 20000
    float* nvOut = npOut + MAX_VOX;                         // 1

    // kInit grid must cover max(G_TOTAL/4, W, MAX_VOX/4) elements
    int mxI = G_TOTAL / 4;
    if (W > mxI) mxI = W;
    int nbI = (mxI + 255) / 256;            // 210
    int nbK = (K + 1023) / 1024;            // 256 (prefix, 4 pts/thread)
    int nbC = (G_TOTAL + 255) / 256;        // 837
    int nbC4 = (G_TOTAL / 4 + 255) / 256;   // 210
    int nbA = ((n >> 2) + 255) / 256;       // 1954 (4 pts/thread)

    kInit<<<nbI, 256, 0, stream>>>(first, rank, bits, vcount, cellOfRank,
                                   dcount, W);
    kPointsFF<<<nbK, 256, 0, stream>>>(pts, first, K);
    countDG<<<nbC4, 256, 0, stream>>>(pts, first, dcount, K, n);
    kMark<<<nbC, 256, 0, stream>>>(first, bits);
    kScan<<<nbW, 256, 0, stream>>>(bits, wordLocal, sums, W);
    kRank<<<nbC, 256, 0, stream>>>(first, bits, wordLocal, sums, nbW, rank,
                                   cellOfRank, nvOut);
    kAppend<<<nbA, 256, 0, stream>>>(pts, rank, vcount, list, n);
    passF<<<MAX_VOX / 4, 256, 0, stream>>>(pts, vcount, cellOfRank, list,
                                           voxOut, coorsOut, npOut);
}

// Round 11
// 118.545 us; speedup vs baseline: 1.0600x; 1.0183x over previous
//
#include <hip/hip_runtime.h>

#define GX 432
#define GY 496
#define G_TOTAL (GX * GY) /* 214272, GZ=1, G_TOTAL%4==0 */
#define MAX_PTS 32
#define MAX_VOX 20000
#define CAP 64
#define INF_SENTINEL 0x7F7F7F7F
#define PREFIX_K 262144 /* ~131k in-range claims -> ~97k distinct cells >> 20000 */

typedef unsigned long long u64;

// IEEE float32 ops exactly matching the reference:
// c = floor((p - lo)/vs), lo = [0, -39.68, -3], vs = [.16,.16,4].
__device__ __forceinline__ int cell_of(float4 p, bool& ok) {
    float fx = floorf((p.x - 0.0f) / 0.16f);
    float fy = floorf((p.y + 39.68f) / 0.16f);
    float fz = floorf((p.z + 3.0f) / 4.0f);
    int cx = (int)fx, cy = (int)fy, cz = (int)fz;
    ok = (cx >= 0 && cx < GX && cy >= 0 && cy < GY && cz == 0);
    return cy * GX + cx;
}

// K1: fused initialization, int4-vectorized (G_TOTAL%4==0, MAX_VOX%4==0).
// rank[] MUST be inited to INF: under the prefix heuristic, cells whose
// first point is >= K are never ranked, but kAppend reads rank[c] for any
// in-range cell (round-4 crash lesson). dcount[0]=distinct count,
// dcount[1]=blocks-done counter for the last-block pattern.
__global__ __launch_bounds__(256) void kInit(int* __restrict__ first,
                                             int* __restrict__ rank,
                                             u64* __restrict__ bits,
                                             int* __restrict__ vcount,
                                             int* __restrict__ cellOfRank,
                                             int* __restrict__ dcount, int W) {
    int i = blockIdx.x * 256 + threadIdx.x;
    const int4 inf4 = make_int4(INF_SENTINEL, INF_SENTINEL, INF_SENTINEL,
                                INF_SENTINEL);
    const int4 m14 = make_int4(-1, -1, -1, -1);
    if (i < G_TOTAL / 4) {
        ((int4*)first)[i] = inf4;
        ((int4*)rank)[i] = inf4;
    }
    if (i < W) bits[i] = 0ull;
    if (i < MAX_VOX / 4) {
        ((int4*)vcount)[i] = m14;
        ((int4*)cellOfRank)[i] = m14;
    }
    if (i < 2) dcount[i] = 0;
}

// K2: FUSED points + distinct-count + guard (best-measured round-8 shape:
// 4 pts/thread x 256 blocks). Distinct count from the atomicMin return
// (old==INF exactly once per cell), LDS-reduced to ONE atomicAdd per block.
// Last-block pattern: threadfence + done-counter; the final block re-reads
// dcount and, ONLY if the prefix yielded < MAX_VOX distinct cells, repairs
// by claiming points K..n itself (filtered atomicMin — exact under stale
// reads since first[] only decreases). Rare path slow (1 block) but correct
// for any input; common path never takes it. Stream order guarantees kMark
// sees the final first[].
__global__ __launch_bounds__(256) void kPointsCG(const float4* __restrict__ pts,
                                                 int* __restrict__ first,
                                                 int* __restrict__ dcount,
                                                 int K, int n) {
    __shared__ int wsh[4];
    __shared__ int repairFlag;
    int t = threadIdx.x;
    int i0 = blockIdx.x * 1024 + t;
    int i1 = i0 + 256, i2 = i0 + 512, i3 = i0 + 768;
    int m = K - 1;
    float4 p0 = pts[i0 < K ? i0 : m];
    float4 p1 = pts[i1 < K ? i1 : m];
    float4 p2 = pts[i2 < K ? i2 : m];
    float4 p3 = pts[i3 < K ? i3 : m];
    bool k0, k1, k2, k3;
    int c0 = cell_of(p0, k0);
    int c1 = cell_of(p1, k1);
    int c2 = cell_of(p2, k2);
    int c3 = cell_of(p3, k3);
    int have = 0;
    if (k0 && i0 < K) have += (atomicMin(&first[c0], i0) == INF_SENTINEL);
    if (k1 && i1 < K) have += (atomicMin(&first[c1], i1) == INF_SENTINEL);
    if (k2 && i2 < K) have += (atomicMin(&first[c2], i2) == INF_SENTINEL);
    if (k3 && i3 < K) have += (atomicMin(&first[c3], i3) == INF_SENTINEL);
    for (int d = 32; d >= 1; d >>= 1) have += __shfl_down(have, d, 64);
    if ((t & 63) == 0) wsh[t >> 6] = have;
    __syncthreads();
    if (t == 0) {
        repairFlag = 0;
        int part = wsh[0] + wsh[1] + wsh[2] + wsh[3];
        if (part) atomicAdd(&dcount[0], part);
        __threadfence();
        if (atomicAdd(&dcount[1], 1) == (int)gridDim.x - 1) {
            // all blocks' dcount contributions are visible (fence-before-done)
            int total = atomicAdd(&dcount[0], 0);
            repairFlag = (total < MAX_VOX);
        }
    }
    __syncthreads();
    if (repairFlag) {
        for (int i = K + t; i < n; i += 256) {
            float4 p = pts[i];
            bool ok;
            int c = cell_of(p, ok);
            if (ok && first[c] > i) atomicMin(&first[c], i);
        }
    }
}

// K3: set bit first[c] in the index-space bitmap. Distinct cells have
// distinct first indices; words shared by ~3 cells -> low-contention atomicOr.
__global__ __launch_bounds__(256) void kMark(const int* __restrict__ first,
                                             u64* __restrict__ bits) {
    int c = blockIdx.x * 256 + threadIdx.x;
    if (c >= G_TOTAL) return;
    int f = first[c];
    if (f != INF_SENTINEL) atomicOr(&bits[f >> 6], 1ull << (f & 63));
}

// K4: per-word intra-block exclusive prefix (wordLocal) + per-block sums.
__global__ __launch_bounds__(256) void kScan(const u64* __restrict__ bits,
                                             unsigned* __restrict__ wordLocal,
                                             int* __restrict__ sums, int W) {
    __shared__ int wsum[4], wexc[4];
    int t = threadIdx.x;
    int wi = blockIdx.x * 256 + t;
    u64 mask = (wi < W) ? bits[wi] : 0ull;
    int v = __popcll(mask);
    int lane = t & 63, w = t >> 6;
    int x = v;
    for (int d = 1; d < 64; d <<= 1) {
        int y = __shfl_up(x, d, 64);
        if (lane >= d) x += y;
    }
    if (lane == 63) wsum[w] = x;
    __syncthreads();
    if (t == 0) {
        int a = 0;
        for (int j = 0; j < 4; j++) { wexc[j] = a; a += wsum[j]; }
        sums[blockIdx.x] = a;
    }
    __syncthreads();
    if (wi < W) wordLocal[wi] = (unsigned)(wexc[w] + x - v);
}

// K5: materialize rank PER CELL (so the 2M-point append pass does only ONE
// random read). Each block redundantly exclusive-scans the (<=256) block
// sums in LDS. Also writes cellOfRank and num_voxels (block 0).
__global__ __launch_bounds__(256) void kRank(const int* __restrict__ first,
                                             const u64* __restrict__ bits,
                                             const unsigned* __restrict__ wordLocal,
                                             const int* __restrict__ sums,
                                             int nbW,
                                             int* __restrict__ rank,
                                             int* __restrict__ cellOfRank,
                                             float* __restrict__ nvOut) {
    __shared__ int sExc[256];
    __shared__ int wsum[4], wexc[4];
    int t = threadIdx.x;
    int v = (t < nbW) ? sums[t] : 0;
    int lane = t & 63, w = t >> 6;
    int x = v;
    for (int d = 1; d < 64; d <<= 1) {
        int y = __shfl_up(x, d, 64);
        if (lane >= d) x += y;
    }
    if (lane == 63) wsum[w] = x;
    __syncthreads();
    if (t == 0) {
        int a = 0;
        for (int j = 0; j < 4; j++) { wexc[j] = a; a += wsum[j]; }
        if (blockIdx.x == 0) nvOut[0] = (float)(a < MAX_VOX ? a : MAX_VOX);
    }
    __syncthreads();
    sExc[t] = wexc[w] + x - v;
    __syncthreads();

    int c = blockIdx.x * 256 + t;
    if (c >= G_TOTAL) return;
    int f = first[c];
    if (f == INF_SENTINEL) return;
    int wf = f >> 6, b = f & 63;
    u64 lowmask = (b == 0) ? 0ull : ((~0ull) >> (64 - b));
    int vr = sExc[wf >> 8] + (int)wordLocal[wf] + __popcll(bits[wf] & lowmask);
    rank[c] = vr;
    if (vr < MAX_VOX) cellOfRank[vr] = c;
}

// K6: append pass, 4 consecutive points/thread (64B contiguous per lane).
// Cells recomputed from pts (bitwise-identical IEEE ops; no lin[] array).
// rank loads issued UNCONDITIONALLY via clamped index (MLP=4 on the 2-level
// pts->rank chain). Unsigned compare (round-4 lesson).
__global__ __launch_bounds__(256) void kAppend(const float4* __restrict__ pts,
                                               const int* __restrict__ rank,
                                               int* __restrict__ vcount,
                                               int* __restrict__ list, int n) {
    int gid = blockIdx.x * 256 + threadIdx.x;
    int nq = n >> 2;
    if (gid < nq) {
        int base = gid * 4;
        float4 p0 = pts[base + 0];
        float4 p1 = pts[base + 1];
        float4 p2 = pts[base + 2];
        float4 p3 = pts[base + 3];
        bool k0, k1, k2, k3;
        int c0 = cell_of(p0, k0);
        int c1 = cell_of(p1, k1);
        int c2 = cell_of(p2, k2);
        int c3 = cell_of(p3, k3);
        int r0 = rank[k0 ? c0 : 0];
        int r1 = rank[k1 ? c1 : 0];
        int r2 = rank[k2 ? c2 : 0];
        int r3 = rank[k3 ? c3 : 0];
        r0 = k0 ? r0 : INF_SENTINEL;
        r1 = k1 ? r1 : INF_SENTINEL;
        r2 = k2 ? r2 : INF_SENTINEL;
        r3 = k3 ? r3 : INF_SENTINEL;
#pragma unroll
        for (int j = 0; j < 4; j++) {
            int vr = j == 0 ? r0 : j == 1 ? r1 : j == 2 ? r2 : r3;
            if ((unsigned)vr >= MAX_VOX) continue;
            int pos = atomicAdd(&vcount[vr], 1) + 1;
            if (pos < CAP) list[vr * CAP + pos] = base + j;
        }
    }
    // scalar tail (n % 4), executed once
    if (gid == 0) {
        for (int i = nq << 2; i < n; i++) {
            float4 p = pts[i];
            bool ok;
            int c = cell_of(p, ok);
            if (!ok) continue;
            int vr = rank[c];
            if ((unsigned)vr >= MAX_VOX) continue;
            int pos = atomicAdd(&vcount[vr], 1) + 1;
            if (pos < CAP) list[vr * CAP + pos] = i;
        }
    }
}

// K7: 4 voxels per 256-thread block (one wave each). Counting-sort the
// collected indices (LDS broadcast reads), write all 32 slots + num_points
// + coors (so no d_out pre-memset is needed).
__global__ __launch_bounds__(256) void passF(const float4* __restrict__ pts,
                                             const int* __restrict__ vcount,
                                             const int* __restrict__ cellOfRank,
                                             const int* __restrict__ list,
                                             float4* __restrict__ voxOut,
                                             float* __restrict__ coorsOut,
                                             float* __restrict__ npOut) {
    __shared__ int s[4][CAP];
    __shared__ int slotPt[4][MAX_PTS];
    int w = threadIdx.x >> 6, lane = threadIdx.x & 63;
    int v = blockIdx.x * 4 + w;
    int cnt = vcount[v] + 1;
    int m = cnt < CAP ? cnt : CAP;
    s[w][lane] = (lane < m) ? list[v * CAP + lane] : 0x7FFFFFFF;
    if (lane < MAX_PTS) slotPt[w][lane] = -1;
    __syncthreads();
    int my = s[w][lane];
    int r = 0;
#pragma unroll
    for (int j = 0; j < CAP; j++) r += (s[w][j] < my) ? 1 : 0;  // broadcast
    if (lane < m && r < MAX_PTS) slotPt[w][r] = my;
    __syncthreads();
    if (lane < MAX_PTS) {
        int p = slotPt[w][lane];
        float4 val = make_float4(0.f, 0.f, 0.f, 0.f);
        if (p >= 0) val = pts[p];
        voxOut[(size_t)v * MAX_PTS + lane] = val;
    }
    if (lane == 0) {
        npOut[v] = (float)(cnt < MAX_PTS ? cnt : MAX_PTS);
        int cell = cellOfRank[v];
        if (cell < 0) {
            coorsOut[3 * v + 0] = -1.0f;
            coorsOut[3 * v + 1] = -1.0f;
            coorsOut[3 * v + 2] = -1.0f;
        } else {
            coorsOut[3 * v + 0] = 0.0f;  // cz (GZ==1)
            coorsOut[3 * v + 1] = (float)(cell / GX);
            coorsOut[3 * v + 2] = (float)(cell % GX);
        }
    }
}

extern "C" void kernel_launch(void* const* d_in, const int* in_sizes, int n_in,
                              void* d_out, int out_size, void* d_ws, size_t ws_size,
                              hipStream_t stream) {
    const float4* pts = (const float4*)d_in[0];
    int n = in_sizes[0] / 4;    // 2,000,000
    int W = (n + 63) >> 6;      // 31250 bitmap words
    int nbW = (W + 255) / 256;  // 123
    int K = PREFIX_K < n ? PREFIX_K : n;

    char* ws = (char*)d_ws;
    size_t off = 0;
    auto alloc = [&](size_t bytes) -> void* {
        void* p = (void*)(ws + off);
        off = (off + bytes + 255) & ~(size_t)255;
        return p;
    };
    int* first = (int*)alloc((size_t)G_TOTAL * 4);
    u64* bits = (u64*)alloc((size_t)W * 8);
    unsigned* wordLocal = (unsigned*)alloc((size_t)W * 4);
    int* sums = (int*)alloc(256 * 4);
    int* rank = (int*)alloc((size_t)G_TOTAL * 4);
    int* vcount = (int*)alloc((size_t)MAX_VOX * 4);
    int* cellOfRank = (int*)alloc((size_t)MAX_VOX * 4);
    int* dcount = (int*)alloc(256 * 4);
    int* list = (int*)alloc((size_t)MAX_VOX * CAP * 4);
    (void)ws_size;
    (void)n_in;
    (void)out_size;

    float* out = (float*)d_out;
    float4* voxOut = (float4*)out;                          // 20000*32*4
    float* coorsOut = out + (size_t)MAX_VOX * MAX_PTS * 4;  // 20000*3
    float* npOut = coorsOut + (size_t)MAX_VOX * 3;          // 20000
    float* nvOut = npOut + MAX_VOX;                         // 1

    // kInit grid must cover max(G_TOTAL/4, W, MAX_VOX/4) elements
    int mxI = G_TOTAL / 4;
    if (W > mxI) mxI = W;
    int nbI = (mxI + 255) / 256;           // 210
    int nbK = (K + 1023) / 1024;           // 256 (prefix, 4 pts/thread)
    int nbC = (G_TOTAL + 255) / 256;       // 837
    int nbA = ((n >> 2) + 255) / 256;      // 1954 (4 pts/thread)

    kInit<<<nbI, 256, 0, stream>>>(first, rank, bits, vcount, cellOfRank,
                                   dcount, W);
    kPointsCG<<<nbK, 256, 0, stream>>>(pts, first, dcount, K, n);
    kMark<<<nbC, 256, 0, stream>>>(first, bits);
    kScan<<<nbW, 256, 0, stream>>>(bits, wordLocal, sums, W);
    kRank<<<nbC, 256, 0, stream>>>(first, bits, wordLocal, sums, nbW, rank,
                                   cellOfRank, nvOut);
    kAppend<<<nbA, 256, 0, stream>>>(pts, rank, vcount, list, n);
    passF<<<MAX_VOX / 4, 256, 0, stream>>>(pts, vcount, cellOfRank, list,
                                           voxOut, coorsOut, npOut);
}